// Round 9
// baseline (168.211 us; speedup 1.0000x reference)
//
#include <hip/hip_runtime.h>

#define RPW 4               // rows per wave (owned end-to-end; no barriers)
#define WAVES 4
#define RPB (RPW * WAVES)   // 16 rows per block
#define NM 14               // Taylor degree (terms 0..14)

using short8 = __attribute__((ext_vector_type(8))) short;
using f32x4  = __attribute__((ext_vector_type(4))) float;

#define LOG2E 1.4426950408889634f

static __device__ __forceinline__ float ex2(float x) { return __builtin_amdgcn_exp2f(x); }
static __device__ __forceinline__ float rcpf_(float x) { return __builtin_amdgcn_rcpf(x); }
static __device__ __forceinline__ float silu_(float x) {
    return x * rcpf_(1.0f + ex2(-x * LOG2E));
}
static __device__ __forceinline__ unsigned short bfhi(float x) {          // truncate
    return (unsigned short)(__float_as_uint(x) >> 16);
}
static __device__ __forceinline__ unsigned short bfrn(float x) {          // round-nearest
    unsigned u = __float_as_uint(x);
    return (unsigned short)((u + 0x7fffu + ((u >> 16) & 1u)) >> 16);
}
static __device__ __forceinline__ float bf2f(unsigned short h) {
    return __uint_as_float(((unsigned)h) << 16);
}

// ---- DPP 16-lane rotation-sum: VALU pipe, zero LDS traffic ------------------
template <int CTRL>
static __device__ __forceinline__ float dpp_rot(float v) {
    return __uint_as_float(
        __builtin_amdgcn_update_dpp(0u, __float_as_uint(v), CTRL, 0xF, 0xF, true));
}
static __device__ __forceinline__ float rsum16(float v) {
    v += dpp_rot<0x128>(v);   // row_ror:8
    v += dpp_rot<0x124>(v);   // row_ror:4
    v += dpp_rot<0x122>(v);   // row_ror:2
    v += dpp_rot<0x121>(v);   // row_ror:1
    return v;
}

__constant__ float c_invfact[15] = {
    1.f, 1.f, 0.5f, 1.f/6, 1.f/24, 1.f/120, 1.f/720, 1.f/5040, 1.f/40320,
    1.f/362880, 1.f/3628800, 1.f/39916800, 1.f/479001600,
    1.f/6227020800.f, 1.f/87178291200.f};

// ---------------- weight prep in d_ws (R6's proven version) ------------------
template <int O, int I>
__device__ __forceinline__ void tr(const float* __restrict__ s, float* __restrict__ d,
                                   int t0, int stride) {
    for (int idx = t0; idx < O * I; idx += stride) {
        int o = idx / I, in = idx - o * I;
        d[in * O + o] = s[idx];
    }
}
template <int TILES, int KTS, int K>
__device__ __forceinline__ void frag_cvt(const float* __restrict__ A,
                                         unsigned short* __restrict__ dst,
                                         int t0, int stride) {
    const int total = TILES * KTS * 2 * 512;
    for (int idx = t0; idx < total; idx += stride) {
        int e = idx & 7;
        int lane = (idx >> 3) & 63;
        int h = (idx >> 9) & 1;
        int kt = (idx >> 10) % KTS;
        int tile = (idx >> 10) / KTS;
        int row = tile * 16 + (lane & 15);
        int col = kt * 32 + (lane >> 4) * 8 + e;
        float a = A[row * K + col];
        unsigned short hi = bfhi(a);
        dst[idx] = h ? bfhi(a - bf2f(hi)) : hi;
    }
}

__global__ void tweights(const float* __restrict__ s0, const float* __restrict__ s1,
                         const float* __restrict__ s2, const float* __restrict__ s3,
                         const float* __restrict__ s4, const float* __restrict__ s5,
                         const float* __restrict__ s6, const float* __restrict__ s7,
                         float* __restrict__ ws) {
    const int stride = gridDim.x * blockDim.x;
    const int t0 = blockIdx.x * blockDim.x + threadIdx.x;
    tr<128, 12>(s0, ws + 0, t0, stride);                       // WinT fp32 [12][128]
    unsigned short* u4 = (unsigned short*)(ws + 1536);
    frag_cvt<8, 4, 128>(s1, u4 + 0,     t0, stride);           // Aq4 frags
    frag_cvt<8, 4, 128>(s2, u4 + 32768, t0, stride);           // Ak4
    frag_cvt<8, 4, 128>(s3, u4 + 65536, t0, stride);           // Av4
    unsigned short* wh = (unsigned short*)(ws + 50688);
    frag_cvt<4, 4, 128>(s4, wh, t0, stride);                   // Wh frags
    unsigned short* u7 = (unsigned short*)(ws + 58880);
    frag_cvt<4, 2, 64>(s5, u7 + 0,     t0, stride);            // Aq7
    frag_cvt<4, 2, 64>(s6, u7 + 8192,  t0, stride);            // Ak7
    frag_cvt<4, 2, 64>(s7, u7 + 16384, t0, stride);            // Av7
}

// ================== fused per-row network — BARRIER-FREE =====================
// Each wave owns 4 rows end-to-end. MFMA phases duplicate the wave's 4 rows
// across the 16-row A-fragment (m16&3); only quad==0 lanes write results.
// Zero __syncthreads: waves drift independently, so one wave's Taylor VALU
// phase overlaps another's MFMA/load phase (convoy breaker). A pseudo-random
// s_sleep stagger seeds the initial drift.
__global__ __launch_bounds__(256, 4) void fused_net(
    const float* __restrict__ x, const float* __restrict__ ws,
    const float* __restrict__ b_in,
    const float* __restrict__ Bq4, const float* __restrict__ Bk4, const float* __restrict__ Bv4,
    const float* __restrict__ b_h,
    const float* __restrict__ Bq7, const float* __restrict__ Bk7, const float* __restrict__ Bv7,
    const float* __restrict__ Wout, const float* __restrict__ b_out,
    float* __restrict__ out) {
    __shared__ __align__(16) unsigned short hAhi[16][136], hAlo[16][136];
    __shared__ __align__(16) unsigned short h2hi[16][80],  h2lo[16][80];
    __shared__ __align__(16) float sQ[16][132];               // q fp32
    __shared__ __align__(16) unsigned short sKVb[16][132][2]; // (k,v) bf16 packed
    __shared__ __align__(16) float h3T[WAVES][64][RPW];       // attn7 out transposed
    __shared__ __align__(16) float sXT[WAVES][12][RPW];
    __shared__ __align__(16) float sY[WAVES][RPW][26];

    const int tid = threadIdx.x;
    const int w = tid >> 6;
    const int l = tid & 63;
    const int row0 = blockIdx.x * RPB + w * RPW;
    const int m16 = l & 15, quad = l >> 4;
    const int m4 = m16 & 3;                // A-frag row -> wave-own row (dup x4)
    const int g = l & 15, r = l >> 4;      // attention mapping: 16 lanes per row
    const int R = w * RPW + r;             // block-row this lane reduces/evaluates

    const float* WinT = ws + 0;                                  // [12][128] fp32
    const unsigned short* F4 = (const unsigned short*)(ws + 1536);
    const unsigned short* WH = (const unsigned short*)(ws + 50688);
    const unsigned short* U7 = (const unsigned short*)(ws + 58880);

    // Phase de-correlation: pseudo-random stagger per (block, wave).
    // 0..7 x s_sleep(8) ~= 0..3.5K cycles (phase duration ~1-2K cycles).
    {
        unsigned hsh = (blockIdx.x * 2654435761u) >> 27;
        int stag = (int)((hsh ^ (unsigned)w) & 7u);
        for (int i = 0; i < stag; i++) __builtin_amdgcn_s_sleep(8);
    }

    // P0: stage x transposed (wave-private; same-wave LDS RAW needs no barrier)
    if (l < 12 * RPW) {
        float v = x[row0 * 12 + l];
        int rr = l / 12, in = l - rr * 12;
        sXT[w][in][rr] = v;
    }

    // P1: h = silu(x @ Win^T + b_in); lane owns cols 2l,2l+1 of wave's 4 rows
    {
        float2 bb = *(const float2*)&b_in[2 * l];
        float a0[RPW], a1[RPW];
        #pragma unroll
        for (int rr = 0; rr < RPW; rr++) { a0[rr] = bb.x; a1[rr] = bb.y; }
        #pragma unroll
        for (int in = 0; in < 12; in++) {
            float2 wv = *(const float2*)&WinT[in * 128 + 2 * l];
            float4 xr = *(const float4*)&sXT[w][in][0];
            a0[0] = fmaf(xr.x, wv.x, a0[0]); a1[0] = fmaf(xr.x, wv.y, a1[0]);
            a0[1] = fmaf(xr.y, wv.x, a0[1]); a1[1] = fmaf(xr.y, wv.y, a1[1]);
            a0[2] = fmaf(xr.z, wv.x, a0[2]); a1[2] = fmaf(xr.z, wv.y, a1[2]);
            a0[3] = fmaf(xr.w, wv.x, a0[3]); a1[3] = fmaf(xr.w, wv.y, a1[3]);
        }
        #pragma unroll
        for (int rr = 0; rr < RPW; rr++) {
            float h0 = silu_(a0[rr]), h1 = silu_(a1[rr]);
            unsigned short h0h = bfhi(h0), h1h = bfhi(h1);
            float r0 = h0 - bf2f(h0h), r1 = h1 - bf2f(h1h);
            *(unsigned*)&hAhi[w * 4 + rr][2 * l] = (unsigned)h0h | ((unsigned)h1h << 16);
            *(unsigned*)&hAlo[w * 4 + rr][2 * l] = (unsigned)bfhi(r0) | ((unsigned)bfhi(r1) << 16);
        }
    }

    // P2: qkv4. Wave computes ALL 24 n-tiles (q,k,v x 8) for its own 4 rows.
    // M=4 duplicated to 16; 3 acc chains of depth 4; rolled loop (no reg blow).
    {
        short8 Ah[4], Al[4];
        #pragma unroll
        for (int kt = 0; kt < 4; kt++) {
            Ah[kt] = *(const short8*)&hAhi[w * 4 + m4][kt * 32 + quad * 8];
            Al[kt] = *(const short8*)&hAlo[w * 4 + m4][kt * 32 + quad * 8];
        }
        #pragma unroll 2
        for (int nt = 0; nt < 24; nt++) {
            const int mat = nt >> 3, tile = nt & 7;
            const int n = tile * 16 + m16;
            const float* bp = (mat == 0) ? Bq4 : (mat == 1) ? Bk4 : Bv4;
            const float b = bp[n];
            f32x4 acc0 = {b, b, b, b};
            f32x4 acc1 = {0.f, 0.f, 0.f, 0.f};
            f32x4 acc2 = {0.f, 0.f, 0.f, 0.f};
            const unsigned short* bq = F4 + mat * 32768 + tile * 4096 + l * 8;
            #pragma unroll
            for (int kt = 0; kt < 4; kt++) {
                short8 bh = *(const short8*)(bq + kt * 1024);
                short8 bl = *(const short8*)(bq + kt * 1024 + 512);
                acc0 = __builtin_amdgcn_mfma_f32_16x16x32_bf16(Ah[kt], bh, acc0, 0, 0, 0);
                acc1 = __builtin_amdgcn_mfma_f32_16x16x32_bf16(Ah[kt], bl, acc1, 0, 0, 0);
                acc2 = __builtin_amdgcn_mfma_f32_16x16x32_bf16(Al[kt], bh, acc2, 0, 0, 0);
            }
            if (quad == 0) {                   // C rows 0..3 = wave rows 0..3
                #pragma unroll
                for (int reg = 0; reg < 4; reg++) {
                    int row = w * 4 + reg;
                    float val = silu_(acc0[reg] + acc1[reg] + acc2[reg]);
                    if (mat == 0)      sQ[row][n] = val;
                    else if (mat == 1) sKVb[row][n][0] = bfrn(val);
                    else               sKVb[row][n][1] = bfrn(val);
                }
            }
        }
    }

    // P3: attention over 128 via Taylor moments. 16 lanes per row (own rows).
    {
        float dmom[NM];       // delta_1..14
        float nmom[NM + 1];   // nu_0..14
        #pragma unroll
        for (int m = 0; m < NM; m++) dmom[m] = 0.f;
        #pragma unroll
        for (int m = 0; m <= NM; m++) nmom[m] = 0.f;
        uint4 u0 = *(const uint4*)&sKVb[R][g * 8][0];
        uint4 u1 = *(const uint4*)&sKVb[R][g * 8 + 4][0];
        unsigned us[8] = {u0.x, u0.y, u0.z, u0.w, u1.x, u1.y, u1.z, u1.w};
        #pragma unroll
        for (int jj = 0; jj < 8; jj++) {
            unsigned u = us[jj];
            float kf = __uint_as_float(u << 16);
            float vf = __uint_as_float(u & 0xffff0000u);
            nmom[0] += vf;
            float p = kf;
            dmom[0] += p; nmom[1] = fmaf(vf, p, nmom[1]);
            #pragma unroll
            for (int m = 1; m < NM; m++) {
                p *= kf;
                dmom[m] += p;
                nmom[m + 1] = fmaf(vf, p, nmom[m + 1]);
            }
        }
        #pragma unroll
        for (int m = 0; m < NM; m++) dmom[m] = rsum16(dmom[m]);
        #pragma unroll
        for (int m = 0; m <= NM; m++) nmom[m] = rsum16(nmom[m]);
        float cd[NM + 1], cn[NM + 1];
        cd[0] = 128.f; cn[0] = nmom[0];
        #pragma unroll
        for (int m = 1; m <= NM; m++) {
            cd[m] = dmom[m - 1] * c_invfact[m];
            cn[m] = nmom[m] * c_invfact[m];
        }
        float4 qa = *(const float4*)&sQ[R][g * 8];
        float4 qb = *(const float4*)&sQ[R][g * 8 + 4];
        float qs[8] = {qa.x, qa.y, qa.z, qa.w, qb.x, qb.y, qb.z, qb.w};
        unsigned hiw[4], low[4];
        #pragma unroll
        for (int i = 0; i < 8; i++) {
            float t = qs[i];
            float d = cd[NM], nn = cn[NM];
            #pragma unroll
            for (int m = NM - 1; m >= 0; m--) {
                d = fmaf(d, t, cd[m]);
                nn = fmaf(nn, t, cn[m]);
            }
            float o = silu_(nn * rcpf_(d));
            unsigned short oh = bfhi(o);
            unsigned short olo = bfhi(o - bf2f(oh));
            if (i & 1) { hiw[i >> 1] |= ((unsigned)oh) << 16; low[i >> 1] |= ((unsigned)olo) << 16; }
            else       { hiw[i >> 1] = oh; low[i >> 1] = olo; }
        }
        *(uint4*)&hAhi[R][g * 8] = make_uint4(hiw[0], hiw[1], hiw[2], hiw[3]);
        *(uint4*)&hAlo[R][g * 8] = make_uint4(low[0], low[1], low[2], low[3]);
    }

    // P4: h2 = silu(attn4 @ Wh^T + b_h). Wave computes all 4 n-tiles, own rows.
    {
        short8 Ah[4], Al[4];
        #pragma unroll
        for (int kt = 0; kt < 4; kt++) {
            Ah[kt] = *(const short8*)&hAhi[w * 4 + m4][kt * 32 + quad * 8];
            Al[kt] = *(const short8*)&hAlo[w * 4 + m4][kt * 32 + quad * 8];
        }
        #pragma unroll 2
        for (int t = 0; t < 4; t++) {
            const int n = t * 16 + m16;
            const float b = b_h[n];
            f32x4 acc0 = {b, b, b, b};
            f32x4 acc1 = {0.f, 0.f, 0.f, 0.f};
            f32x4 acc2 = {0.f, 0.f, 0.f, 0.f};
            const unsigned short* bq = WH + t * 4096 + l * 8;
            #pragma unroll
            for (int kt = 0; kt < 4; kt++) {
                short8 bh = *(const short8*)(bq + kt * 1024);
                short8 bl = *(const short8*)(bq + kt * 1024 + 512);
                acc0 = __builtin_amdgcn_mfma_f32_16x16x32_bf16(Ah[kt], bh, acc0, 0, 0, 0);
                acc1 = __builtin_amdgcn_mfma_f32_16x16x32_bf16(Ah[kt], bl, acc1, 0, 0, 0);
                acc2 = __builtin_amdgcn_mfma_f32_16x16x32_bf16(Al[kt], bh, acc2, 0, 0, 0);
            }
            if (quad == 0) {
                #pragma unroll
                for (int reg = 0; reg < 4; reg++) {
                    int row = w * 4 + reg;
                    float hv = silu_(acc0[reg] + acc1[reg] + acc2[reg]);
                    unsigned short hh = bfhi(hv);
                    h2hi[row][n] = hh;
                    h2lo[row][n] = bfhi(hv - bf2f(hh));
                }
            }
        }
    }

    // P5: qkv7. Wave computes all 12 n-tiles (q,k,v x 4), own rows. K=64.
    {
        short8 Ah[2], Al[2];
        #pragma unroll
        for (int kt = 0; kt < 2; kt++) {
            Ah[kt] = *(const short8*)&h2hi[w * 4 + m4][kt * 32 + quad * 8];
            Al[kt] = *(const short8*)&h2lo[w * 4 + m4][kt * 32 + quad * 8];
        }
        #pragma unroll 2
        for (int nt = 0; nt < 12; nt++) {
            const int mat = nt >> 2, tile = nt & 3;
            const int n = tile * 16 + m16;
            const float* bp = (mat == 0) ? Bq7 : (mat == 1) ? Bk7 : Bv7;
            const float b = bp[n];
            f32x4 acc0 = {b, b, b, b};
            f32x4 acc1 = {0.f, 0.f, 0.f, 0.f};
            f32x4 acc2 = {0.f, 0.f, 0.f, 0.f};
            const unsigned short* bq = U7 + mat * 8192 + tile * 2048 + l * 8;
            #pragma unroll
            for (int kt = 0; kt < 2; kt++) {
                short8 bh = *(const short8*)(bq + kt * 1024);
                short8 bl = *(const short8*)(bq + kt * 1024 + 512);
                acc0 = __builtin_amdgcn_mfma_f32_16x16x32_bf16(Ah[kt], bh, acc0, 0, 0, 0);
                acc1 = __builtin_amdgcn_mfma_f32_16x16x32_bf16(Ah[kt], bl, acc1, 0, 0, 0);
                acc2 = __builtin_amdgcn_mfma_f32_16x16x32_bf16(Al[kt], bh, acc2, 0, 0, 0);
            }
            if (quad == 0) {
                #pragma unroll
                for (int reg = 0; reg < 4; reg++) {
                    int row = w * 4 + reg;
                    float val = silu_(acc0[reg] + acc1[reg] + acc2[reg]);
                    if (mat == 0)      sQ[row][n] = val;
                    else if (mat == 1) sKVb[row][n][0] = bfrn(val);
                    else               sKVb[row][n][1] = bfrn(val);
                }
            }
        }
    }

    // P6: attention over 64 via Taylor moments; lane: j,i in g*4..g*4+3
    {
        float dmom[NM];
        float nmom[NM + 1];
        #pragma unroll
        for (int m = 0; m < NM; m++) dmom[m] = 0.f;
        #pragma unroll
        for (int m = 0; m <= NM; m++) nmom[m] = 0.f;
        uint2 u0 = *(const uint2*)&sKVb[R][g * 4][0];
        uint2 u1 = *(const uint2*)&sKVb[R][g * 4 + 2][0];
        unsigned us[4] = {u0.x, u0.y, u1.x, u1.y};
        #pragma unroll
        for (int jj = 0; jj < 4; jj++) {
            unsigned u = us[jj];
            float kf = __uint_as_float(u << 16);
            float vf = __uint_as_float(u & 0xffff0000u);
            nmom[0] += vf;
            float p = kf;
            dmom[0] += p; nmom[1] = fmaf(vf, p, nmom[1]);
            #pragma unroll
            for (int m = 1; m < NM; m++) {
                p *= kf;
                dmom[m] += p;
                nmom[m + 1] = fmaf(vf, p, nmom[m + 1]);
            }
        }
        #pragma unroll
        for (int m = 0; m < NM; m++) dmom[m] = rsum16(dmom[m]);
        #pragma unroll
        for (int m = 0; m <= NM; m++) nmom[m] = rsum16(nmom[m]);
        float cd[NM + 1], cn[NM + 1];
        cd[0] = 64.f; cn[0] = nmom[0];
        #pragma unroll
        for (int m = 1; m <= NM; m++) {
            cd[m] = dmom[m - 1] * c_invfact[m];
            cn[m] = nmom[m] * c_invfact[m];
        }
        float4 qa = *(const float4*)&sQ[R][g * 4];
        float qs[4] = {qa.x, qa.y, qa.z, qa.w};
        #pragma unroll
        for (int i = 0; i < 4; i++) {
            float t = qs[i];
            float d = cd[NM], nn = cn[NM];
            #pragma unroll
            for (int m = NM - 1; m >= 0; m--) {
                d = fmaf(d, t, cd[m]);
                nn = fmaf(nn, t, cn[m]);
            }
            h3T[w][g * 4 + i][r] = silu_(nn * rcpf_(d));
        }
    }

    // P7: y = silu(attn7 @ Wout^T + b_out), 64 -> 25, split across lane halves
    {
        const int o = l & 31;
        const int half = l >> 5;
        const int oc = (o < 25) ? o : 0;
        float y[RPW];
        float bb = (half == 0) ? b_out[oc] : 0.f;
        #pragma unroll
        for (int rr = 0; rr < RPW; rr++) y[rr] = bb;
        const int in0 = half * 32;
        const float* wp = Wout + oc * 64 + in0;
        #pragma unroll
        for (int q = 0; q < 8; q++) {
            float4 wq = *(const float4*)&wp[4 * q];
            float wa[4] = {wq.x, wq.y, wq.z, wq.w};
            #pragma unroll
            for (int ii = 0; ii < 4; ii++) {
                int in = in0 + 4 * q + ii;
                float4 xr = *(const float4*)&h3T[w][in][0];
                y[0] = fmaf(xr.x, wa[ii], y[0]);
                y[1] = fmaf(xr.y, wa[ii], y[1]);
                y[2] = fmaf(xr.z, wa[ii], y[2]);
                y[3] = fmaf(xr.w, wa[ii], y[3]);
            }
        }
        #pragma unroll
        for (int rr = 0; rr < RPW; rr++) {
            float full = y[rr] + __shfl_xor(y[rr], 32, 64);
            if (l < 25) sY[w][rr][l] = silu_(full);
        }
    }

    // P8: quadratic epilogue; lanes l < RPW, one row each
    if (l < RPW) {
        const int rr = l;
        float y[25];
        #pragma unroll
        for (int c = 0; c < 25; c++) y[c] = sY[w][rr][c];
        float M11 = 0.f, M12 = 0.f, M21 = 0.f, M22 = 0.f, Mpp = 0.f;
        #pragma unroll
        for (int c = 0; c < 5; c++) {
            M11 = fmaf(y[c], y[c], M11);
            M12 = fmaf(y[5 + c], y[5 + c], M12);
            M21 = fmaf(y[10 + c], y[10 + c], M21);
            M22 = fmaf(y[15 + c], y[15 + c], M22);
            Mpp = fmaf(y[20 + c], y[20 + c], Mpp);
        }
        float quad_ = M11 * (y[0] * y[0] + y[1] * y[1])
                    + (M12 + M21) * (y[0] * y[2] + y[1] * y[3])
                    + M22 * (y[2] * y[2] + y[3] * y[3]);
        out[row0 + rr] = quad_ + Mpp;
    }
}

extern "C" void kernel_launch(void* const* d_in, const int* in_sizes, int n_in,
                              void* d_out, int out_size, void* d_ws, size_t ws_size,
                              hipStream_t stream) {
    const float* x    = (const float*)d_in[0];
    const float* W_in = (const float*)d_in[2];
    const float* b_in = (const float*)d_in[3];
    const float* Aq4  = (const float*)d_in[4];
    const float* Bq4  = (const float*)d_in[5];
    const float* Ak4  = (const float*)d_in[6];
    const float* Bk4  = (const float*)d_in[7];
    const float* Av4  = (const float*)d_in[8];
    const float* Bv4  = (const float*)d_in[9];
    const float* W_h  = (const float*)d_in[10];
    const float* b_h  = (const float*)d_in[11];
    const float* Aq7  = (const float*)d_in[12];
    const float* Bq7  = (const float*)d_in[13];
    const float* Ak7  = (const float*)d_in[14];
    const float* Bk7  = (const float*)d_in[15];
    const float* Av7  = (const float*)d_in[16];
    const float* Bv7  = (const float*)d_in[17];
    const float* Wout = (const float*)d_in[18];
    const float* bout = (const float*)d_in[19];
    float* ws = (float*)d_ws;

    tweights<<<256, 256, 0, stream>>>(W_in, Aq4, Ak4, Av4, W_h, Aq7, Ak7, Av7, ws);

    const int B = in_sizes[0] / 12;        // 16384
    const int grid = B / RPB;              // 1024
    fused_net<<<grid, 256, 0, stream>>>(x, ws, b_in, Bq4, Bk4, Bv4,
                                        b_h, Bq7, Bk7, Bv7, Wout, bout, (float*)d_out);
}

// Round 10
// 120.276 us; speedup vs baseline: 1.3985x; 1.3985x over previous
//
#include <hip/hip_runtime.h>

#define RPW 4            // rows per wave
#define WAVES 4
#define RPB (RPW * WAVES)   // 16 rows per block
#define NM 14               // Taylor degree (terms 0..14)

using short8 = __attribute__((ext_vector_type(8))) short;
using f32x4  = __attribute__((ext_vector_type(4))) float;

#define LOG2E 1.4426950408889634f

static __device__ __forceinline__ float ex2(float x) { return __builtin_amdgcn_exp2f(x); }
static __device__ __forceinline__ float rcpf_(float x) { return __builtin_amdgcn_rcpf(x); }
static __device__ __forceinline__ float silu_(float x) {
    return x * rcpf_(1.0f + ex2(-x * LOG2E));
}
static __device__ __forceinline__ unsigned short bfhi(float x) {          // truncate
    return (unsigned short)(__float_as_uint(x) >> 16);
}
static __device__ __forceinline__ unsigned short bfrn(float x) {          // round-nearest
    unsigned u = __float_as_uint(x);
    return (unsigned short)((u + 0x7fffu + ((u >> 16) & 1u)) >> 16);
}
static __device__ __forceinline__ float bf2f(unsigned short h) {
    return __uint_as_float(((unsigned)h) << 16);
}

// ---- DPP 16-lane rotation-sum: VALU pipe, zero LDS traffic ------------------
template <int CTRL>
static __device__ __forceinline__ float dpp_rot(float v) {
    return __uint_as_float(
        __builtin_amdgcn_update_dpp(0u, __float_as_uint(v), CTRL, 0xF, 0xF, true));
}
static __device__ __forceinline__ float rsum16(float v) {
    v += dpp_rot<0x128>(v);   // row_ror:8
    v += dpp_rot<0x124>(v);   // row_ror:4
    v += dpp_rot<0x122>(v);   // row_ror:2
    v += dpp_rot<0x121>(v);   // row_ror:1
    return v;
}

__constant__ float c_invfact[15] = {
    1.f, 1.f, 0.5f, 1.f/6, 1.f/24, 1.f/120, 1.f/720, 1.f/5040, 1.f/40320,
    1.f/362880, 1.f/3628800, 1.f/39916800, 1.f/479001600,
    1.f/6227020800.f, 1.f/87178291200.f};

// ---------------- weight prep in d_ws ---------------------------------------
template <int O, int I>
__device__ __forceinline__ void tr(const float* __restrict__ s, float* __restrict__ d,
                                   int t0, int stride) {
    for (int idx = t0; idx < O * I; idx += stride) {
        int o = idx / I, in = idx - o * I;
        d[in * O + o] = s[idx];
    }
}

// MFMA-fragment-ordered bf16 hi/lo split (proven in R6, absmax=0):
// dst[tile*KTS*1024 + kt*1024 + h*512 + lane*8 + e] =
//   (h ? lo : hi) of A[tile*16 + (lane&15)][kt*32 + (lane>>4)*8 + e]
// -> consumption: lane l reads 16B at dst + tile*... + kt*1024 (+512 for lo)
//    + l*8: one fully-coalesced 1 KB wave load per fragment (16 L2 lines
//    instead of the 64-line gather of the [o][in] layout).
template <int TILES, int KTS, int K>
__device__ __forceinline__ void frag_cvt(const float* __restrict__ A,
                                         unsigned short* __restrict__ dst,
                                         int t0, int stride) {
    const int total = TILES * KTS * 2 * 512;
    for (int idx = t0; idx < total; idx += stride) {
        int e = idx & 7;
        int lane = (idx >> 3) & 63;
        int h = (idx >> 9) & 1;
        int kt = (idx >> 10) % KTS;
        int tile = (idx >> 10) / KTS;
        int row = tile * 16 + (lane & 15);
        int col = kt * 32 + (lane >> 4) * 8 + e;
        float a = A[row * K + col];
        unsigned short hi = bfhi(a);
        dst[idx] = h ? bfhi(a - bf2f(hi)) : hi;
    }
}

__global__ void tweights(const float* __restrict__ s0, const float* __restrict__ s1,
                         const float* __restrict__ s2, const float* __restrict__ s3,
                         const float* __restrict__ s4, const float* __restrict__ s5,
                         const float* __restrict__ s6, const float* __restrict__ s7,
                         const float* __restrict__ s8, float* __restrict__ ws) {
    const int stride = gridDim.x * blockDim.x;
    const int t0 = blockIdx.x * blockDim.x + threadIdx.x;
    tr<128, 12>(s0, ws + 0, t0, stride);                       // WinT fp32 [12][128]
    unsigned short* u4 = (unsigned short*)(ws + 1536);
    frag_cvt<8, 4, 128>(s1, u4 + 0,     t0, stride);           // Aq4 frags
    frag_cvt<8, 4, 128>(s2, u4 + 32768, t0, stride);           // Ak4
    frag_cvt<8, 4, 128>(s3, u4 + 65536, t0, stride);           // Av4
    unsigned short* wh = (unsigned short*)(ws + 50688);
    frag_cvt<4, 4, 128>(s4, wh, t0, stride);                   // Wh frags
    unsigned short* u7 = (unsigned short*)(ws + 58880);
    frag_cvt<4, 2, 64>(s5, u7 + 0,     t0, stride);            // Aq7
    frag_cvt<4, 2, 64>(s6, u7 + 8192,  t0, stride);            // Ak7
    frag_cvt<4, 2, 64>(s7, u7 + 16384, t0, stride);            // Av7
    tr<25, 64>(s8, ws + 71168, t0, stride);                    // WoutT fp32 [64][25]
}

// ---------------- fused per-row network ------------------------------------
// R0 structure byte-for-byte (52 VGPR, no spill, 47.2 us proven) with EXACTLY
// ONE change: P2/P4/P5 B-fragment loads use the fragment-ordered layout
// (coalesced 1 KB wave loads) instead of 64-line gathers. No prefetch arrays,
// no bias arrays -- isolates the coalescing variable from register pressure.
__global__ __launch_bounds__(256, 4) void fused_net(
    const float* __restrict__ x, const float* __restrict__ ws,
    const float* __restrict__ b_in,
    const float* __restrict__ Bq4, const float* __restrict__ Bk4, const float* __restrict__ Bv4,
    const float* __restrict__ b_h,
    const float* __restrict__ Bq7, const float* __restrict__ Bk7, const float* __restrict__ Bv7,
    const float* __restrict__ b_out,
    float* __restrict__ out) {
    __shared__ __align__(16) unsigned short hAhi[16][136], hAlo[16][136];
    __shared__ __align__(16) unsigned short h2hi[16][80],  h2lo[16][80];
    __shared__ __align__(16) float sQ[16][132];               // q fp32
    __shared__ __align__(16) unsigned short sKVb[16][132][2]; // (k,v) bf16 packed
    __shared__ __align__(16) float h3T[WAVES][64][RPW];       // attn7 out transposed
    __shared__ __align__(16) float sXT[WAVES][12][RPW];
    __shared__ __align__(16) float sY[WAVES][RPW][26];

    const int tid = threadIdx.x;
    const int w = tid >> 6;
    const int l = tid & 63;
    const int row0 = blockIdx.x * RPB + w * RPW;
    const int m16 = l & 15, quad = l >> 4;
    const int g = l & 15, r = l >> 4;      // attention mapping: 16 lanes per row
    const int R = w * RPW + r;             // block-row this lane reduces/evaluates

    const float* WinT  = ws + 0;      // [12][128] fp32
    const float* WoutT = ws + 71168;  // [64][25]  fp32

    // P0: stage x transposed (wave-private)
    if (l < 12 * RPW) {
        float v = x[row0 * 12 + l];
        int rr = l / 12, in = l - rr * 12;
        sXT[w][in][rr] = v;
    }

    // P1: h = silu(x @ Win^T + b_in); lane owns cols 2l,2l+1 -> hA bf16 hi/lo
    {
        float2 bb = *(const float2*)&b_in[2 * l];
        float a0[RPW], a1[RPW];
        #pragma unroll
        for (int rr = 0; rr < RPW; rr++) { a0[rr] = bb.x; a1[rr] = bb.y; }
        #pragma unroll
        for (int in = 0; in < 12; in++) {
            float2 wv = *(const float2*)&WinT[in * 128 + 2 * l];
            float4 xr = *(const float4*)&sXT[w][in][0];
            a0[0] = fmaf(xr.x, wv.x, a0[0]); a1[0] = fmaf(xr.x, wv.y, a1[0]);
            a0[1] = fmaf(xr.y, wv.x, a0[1]); a1[1] = fmaf(xr.y, wv.y, a1[1]);
            a0[2] = fmaf(xr.z, wv.x, a0[2]); a1[2] = fmaf(xr.z, wv.y, a1[2]);
            a0[3] = fmaf(xr.w, wv.x, a0[3]); a1[3] = fmaf(xr.w, wv.y, a1[3]);
        }
        #pragma unroll
        for (int rr = 0; rr < RPW; rr++) {
            float h0 = silu_(a0[rr]), h1 = silu_(a1[rr]);
            unsigned short h0h = bfhi(h0), h1h = bfhi(h1);
            float r0 = h0 - bf2f(h0h), r1 = h1 - bf2f(h1h);
            *(unsigned*)&hAhi[w * 4 + rr][2 * l] = (unsigned)h0h | ((unsigned)h1h << 16);
            *(unsigned*)&hAlo[w * 4 + rr][2 * l] = (unsigned)bfhi(r0) | ((unsigned)bfhi(r1) << 16);
        }
    }
    __syncthreads();

    // P2: qkv4 via MFMA bf16x3. M=16, K=128, N=384. wave w: n-tiles w*6..w*6+5
    // B loads: fragment-ordered, coalesced 1 KB per wave per fragment.
    {
        short8 Ah[4], Al[4];
        #pragma unroll
        for (int kt = 0; kt < 4; kt++) {
            Ah[kt] = *(const short8*)&hAhi[m16][kt * 32 + quad * 8];
            Al[kt] = *(const short8*)&hAlo[m16][kt * 32 + quad * 8];
        }
        const unsigned short* u4 = (const unsigned short*)(ws + 1536);
        #pragma unroll
        for (int t = 0; t < 6; t++) {
            const int nt = w * 6 + t;
            const int mat = nt >> 3;           // 0=q,1=k,2=v (wave-uniform)
            const int n = (nt & 7) * 16 + m16;
            const float* bp = (mat == 0) ? Bq4 : (mat == 1) ? Bk4 : Bv4;
            float b = bp[n];
            f32x4 acc = {b, b, b, b};
            const unsigned short* fq = u4 + mat * 32768 + (nt & 7) * 4096 + l * 8;
            #pragma unroll
            for (int kt = 0; kt < 4; kt++) {
                short8 bh = *(const short8*)(fq + kt * 1024);
                short8 bl = *(const short8*)(fq + kt * 1024 + 512);
                acc = __builtin_amdgcn_mfma_f32_16x16x32_bf16(Ah[kt], bh, acc, 0, 0, 0);
                acc = __builtin_amdgcn_mfma_f32_16x16x32_bf16(Ah[kt], bl, acc, 0, 0, 0);
                acc = __builtin_amdgcn_mfma_f32_16x16x32_bf16(Al[kt], bh, acc, 0, 0, 0);
            }
            #pragma unroll
            for (int reg = 0; reg < 4; reg++) {
                int row = quad * 4 + reg;
                float val = silu_(acc[reg]);
                if (mat == 0)      sQ[row][n] = val;
                else if (mat == 1) sKVb[row][n][0] = bfrn(val);
                else               sKVb[row][n][1] = bfrn(val);
            }
        }
    }
    __syncthreads();

    // P3: attention over 128 via Taylor moments. 16 lanes per row; lane: j,i in g*8..g*8+7
    {
        float dmom[NM];       // delta_1..14
        float nmom[NM + 1];   // nu_0..14
        #pragma unroll
        for (int m = 0; m < NM; m++) dmom[m] = 0.f;
        #pragma unroll
        for (int m = 0; m <= NM; m++) nmom[m] = 0.f;
        uint4 u0 = *(const uint4*)&sKVb[R][g * 8][0];
        uint4 u1 = *(const uint4*)&sKVb[R][g * 8 + 4][0];
        unsigned us[8] = {u0.x, u0.y, u0.z, u0.w, u1.x, u1.y, u1.z, u1.w};
        #pragma unroll
        for (int jj = 0; jj < 8; jj++) {
            unsigned u = us[jj];
            float kf = __uint_as_float(u << 16);
            float vf = __uint_as_float(u & 0xffff0000u);
            nmom[0] += vf;
            float p = kf;
            dmom[0] += p; nmom[1] = fmaf(vf, p, nmom[1]);
            #pragma unroll
            for (int m = 1; m < NM; m++) {
                p *= kf;
                dmom[m] += p;
                nmom[m + 1] = fmaf(vf, p, nmom[m + 1]);
            }
        }
        #pragma unroll
        for (int m = 0; m < NM; m++) dmom[m] = rsum16(dmom[m]);
        #pragma unroll
        for (int m = 0; m <= NM; m++) nmom[m] = rsum16(nmom[m]);
        float cd[NM + 1], cn[NM + 1];
        cd[0] = 128.f; cn[0] = nmom[0];
        #pragma unroll
        for (int m = 1; m <= NM; m++) {
            cd[m] = dmom[m - 1] * c_invfact[m];
            cn[m] = nmom[m] * c_invfact[m];
        }
        float4 qa = *(const float4*)&sQ[R][g * 8];
        float4 qb = *(const float4*)&sQ[R][g * 8 + 4];
        float qs[8] = {qa.x, qa.y, qa.z, qa.w, qb.x, qb.y, qb.z, qb.w};
        unsigned hiw[4], low[4];
        #pragma unroll
        for (int i = 0; i < 8; i++) {
            float t = qs[i];
            float d = cd[NM], nn = cn[NM];
            #pragma unroll
            for (int m = NM - 1; m >= 0; m--) {
                d = fmaf(d, t, cd[m]);
                nn = fmaf(nn, t, cn[m]);
            }
            float o = silu_(nn * rcpf_(d));
            unsigned short oh = bfhi(o);
            unsigned short olo = bfhi(o - bf2f(oh));
            if (i & 1) { hiw[i >> 1] |= ((unsigned)oh) << 16; low[i >> 1] |= ((unsigned)olo) << 16; }
            else       { hiw[i >> 1] = oh; low[i >> 1] = olo; }
        }
        *(uint4*)&hAhi[R][g * 8] = make_uint4(hiw[0], hiw[1], hiw[2], hiw[3]);
        *(uint4*)&hAlo[R][g * 8] = make_uint4(low[0], low[1], low[2], low[3]);
    }
    __syncthreads();

    // P4: h2 = silu(attn4 @ Wh^T + b_h) via MFMA bf16x3. K=128, N=64; wave w: tile w
    {
        short8 Ah[4], Al[4];
        #pragma unroll
        for (int kt = 0; kt < 4; kt++) {
            Ah[kt] = *(const short8*)&hAhi[m16][kt * 32 + quad * 8];
            Al[kt] = *(const short8*)&hAlo[m16][kt * 32 + quad * 8];
        }
        const unsigned short* WH = (const unsigned short*)(ws + 50688);
        const unsigned short* fq = WH + w * 4096 + l * 8;
        const int n = w * 16 + m16;
        float b = b_h[n];
        f32x4 acc = {b, b, b, b};
        #pragma unroll
        for (int kt = 0; kt < 4; kt++) {
            short8 bh = *(const short8*)(fq + kt * 1024);
            short8 bl = *(const short8*)(fq + kt * 1024 + 512);
            acc = __builtin_amdgcn_mfma_f32_16x16x32_bf16(Ah[kt], bh, acc, 0, 0, 0);
            acc = __builtin_amdgcn_mfma_f32_16x16x32_bf16(Ah[kt], bl, acc, 0, 0, 0);
            acc = __builtin_amdgcn_mfma_f32_16x16x32_bf16(Al[kt], bh, acc, 0, 0, 0);
        }
        #pragma unroll
        for (int reg = 0; reg < 4; reg++) {
            int row = quad * 4 + reg;
            float hv = silu_(acc[reg]);
            unsigned short hh = bfhi(hv);
            h2hi[row][n] = hh;
            h2lo[row][n] = bfhi(hv - bf2f(hh));
        }
    }
    __syncthreads();

    // P5: qkv7 via MFMA bf16x3. M=16, K=64, N=192. wave w: nt = w*3..w*3+2
    {
        short8 Ah[2], Al[2];
        #pragma unroll
        for (int kt = 0; kt < 2; kt++) {
            Ah[kt] = *(const short8*)&h2hi[m16][kt * 32 + quad * 8];
            Al[kt] = *(const short8*)&h2lo[m16][kt * 32 + quad * 8];
        }
        const unsigned short* u7 = (const unsigned short*)(ws + 58880);
        #pragma unroll
        for (int t = 0; t < 3; t++) {
            const int nt = w * 3 + t;
            const int mat = nt >> 2;           // 0=q,1=k,2=v
            const int n = (nt & 3) * 16 + m16;
            const float* bp = (mat == 0) ? Bq7 : (mat == 1) ? Bk7 : Bv7;
            float b = bp[n];
            f32x4 acc = {b, b, b, b};
            const unsigned short* fq = u7 + mat * 8192 + (nt & 3) * 2048 + l * 8;
            #pragma unroll
            for (int kt = 0; kt < 2; kt++) {
                short8 bh = *(const short8*)(fq + kt * 1024);
                short8 bl = *(const short8*)(fq + kt * 1024 + 512);
                acc = __builtin_amdgcn_mfma_f32_16x16x32_bf16(Ah[kt], bh, acc, 0, 0, 0);
                acc = __builtin_amdgcn_mfma_f32_16x16x32_bf16(Ah[kt], bl, acc, 0, 0, 0);
                acc = __builtin_amdgcn_mfma_f32_16x16x32_bf16(Al[kt], bh, acc, 0, 0, 0);
            }
            #pragma unroll
            for (int reg = 0; reg < 4; reg++) {
                int row = quad * 4 + reg;
                float val = silu_(acc[reg]);
                if (mat == 0)      sQ[row][n] = val;
                else if (mat == 1) sKVb[row][n][0] = bfrn(val);
                else               sKVb[row][n][1] = bfrn(val);
            }
        }
    }
    __syncthreads();

    // P6: attention over 64 via Taylor moments; lane: j,i in g*4..g*4+3
    {
        float dmom[NM];
        float nmom[NM + 1];
        #pragma unroll
        for (int m = 0; m < NM; m++) dmom[m] = 0.f;
        #pragma unroll
        for (int m = 0; m <= NM; m++) nmom[m] = 0.f;
        uint2 u0 = *(const uint2*)&sKVb[R][g * 4][0];
        uint2 u1 = *(const uint2*)&sKVb[R][g * 4 + 2][0];
        unsigned us[4] = {u0.x, u0.y, u1.x, u1.y};
        #pragma unroll
        for (int jj = 0; jj < 4; jj++) {
            unsigned u = us[jj];
            float kf = __uint_as_float(u << 16);
            float vf = __uint_as_float(u & 0xffff0000u);
            nmom[0] += vf;
            float p = kf;
            dmom[0] += p; nmom[1] = fmaf(vf, p, nmom[1]);
            #pragma unroll
            for (int m = 1; m < NM; m++) {
                p *= kf;
                dmom[m] += p;
                nmom[m + 1] = fmaf(vf, p, nmom[m + 1]);
            }
        }
        #pragma unroll
        for (int m = 0; m < NM; m++) dmom[m] = rsum16(dmom[m]);
        #pragma unroll
        for (int m = 0; m <= NM; m++) nmom[m] = rsum16(nmom[m]);
        float cd[NM + 1], cn[NM + 1];
        cd[0] = 64.f; cn[0] = nmom[0];
        #pragma unroll
        for (int m = 1; m <= NM; m++) {
            cd[m] = dmom[m - 1] * c_invfact[m];
            cn[m] = nmom[m] * c_invfact[m];
        }
        float4 qa = *(const float4*)&sQ[R][g * 4];
        float qs[4] = {qa.x, qa.y, qa.z, qa.w};
        #pragma unroll
        for (int i = 0; i < 4; i++) {
            float t = qs[i];
            float d = cd[NM], nn = cn[NM];
            #pragma unroll
            for (int m = NM - 1; m >= 0; m--) {
                d = fmaf(d, t, cd[m]);
                nn = fmaf(nn, t, cn[m]);
            }
            h3T[w][g * 4 + i][r] = silu_(nn * rcpf_(d));
        }
    }
    // h3T slice is wave-private from here on — no block sync needed.

    // P7: y = silu(attn7 @ Wout^T + b_out), 64 -> 25, split across lane halves
    {
        const int o = l & 31;
        const int half = l >> 5;
        const int oc = (o < 25) ? o : 0;
        float y[RPW];
        float bb = (half == 0) ? b_out[oc] : 0.f;
        #pragma unroll
        for (int rr = 0; rr < RPW; rr++) y[rr] = bb;
        const int in0 = half * 32;
        #pragma unroll 4
        for (int i = 0; i < 32; i++) {
            int in = in0 + i;
            float wv = WoutT[in * 25 + oc];
            float4 xr = *(const float4*)&h3T[w][in][0];
            y[0] = fmaf(xr.x, wv, y[0]);
            y[1] = fmaf(xr.y, wv, y[1]);
            y[2] = fmaf(xr.z, wv, y[2]);
            y[3] = fmaf(xr.w, wv, y[3]);
        }
        #pragma unroll
        for (int rr = 0; rr < RPW; rr++) {
            float full = y[rr] + __shfl_xor(y[rr], 32, 64);
            if (l < 25) sY[w][rr][l] = silu_(full);
        }
    }

    // P8: quadratic epilogue; lanes l < RPW, one row each
    if (l < RPW) {
        const int rr = l;
        float y[25];
        #pragma unroll
        for (int c = 0; c < 25; c++) y[c] = sY[w][rr][c];
        float M11 = 0.f, M12 = 0.f, M21 = 0.f, M22 = 0.f, Mpp = 0.f;
        #pragma unroll
        for (int c = 0; c < 5; c++) {
            M11 = fmaf(y[c], y[c], M11);
            M12 = fmaf(y[5 + c], y[5 + c], M12);
            M21 = fmaf(y[10 + c], y[10 + c], M21);
            M22 = fmaf(y[15 + c], y[15 + c], M22);
            Mpp = fmaf(y[20 + c], y[20 + c], Mpp);
        }
        float quad = M11 * (y[0] * y[0] + y[1] * y[1])
                   + (M12 + M21) * (y[0] * y[2] + y[1] * y[3])
                   + M22 * (y[2] * y[2] + y[3] * y[3]);
        out[row0 + rr] = quad + Mpp;
    }
}

extern "C" void kernel_launch(void* const* d_in, const int* in_sizes, int n_in,
                              void* d_out, int out_size, void* d_ws, size_t ws_size,
                              hipStream_t stream) {
    const float* x    = (const float*)d_in[0];
    const float* W_in = (const float*)d_in[2];
    const float* b_in = (const float*)d_in[3];
    const float* Aq4  = (const float*)d_in[4];
    const float* Bq4  = (const float*)d_in[5];
    const float* Ak4  = (const float*)d_in[6];
    const float* Bk4  = (const float*)d_in[7];
    const float* Av4  = (const float*)d_in[8];
    const float* Bv4  = (const float*)d_in[9];
    const float* W_h  = (const float*)d_in[10];
    const float* b_h  = (const float*)d_in[11];
    const float* Aq7  = (const float*)d_in[12];
    const float* Bq7  = (const float*)d_in[13];
    const float* Ak7  = (const float*)d_in[14];
    const float* Bk7  = (const float*)d_in[15];
    const float* Av7  = (const float*)d_in[16];
    const float* Bv7  = (const float*)d_in[17];
    const float* Wout = (const float*)d_in[18];
    const float* bout = (const float*)d_in[19];
    float* ws = (float*)d_ws;

    tweights<<<256, 256, 0, stream>>>(W_in, Aq4, Ak4, Av4, W_h, Aq7, Ak7, Av7, Wout, ws);

    const int B = in_sizes[0] / 12;        // 16384
    const int grid = B / RPB;              // 1024
    fused_net<<<grid, 256, 0, stream>>>(x, ws, b_in, Bq4, Bk4, Bv4,
                                        b_h, Bq7, Bk7, Bv7, bout, (float*)d_out);
}